// Round 1
// baseline (2355.827 us; speedup 1.0000x reference)
//
#include <hip/hip_runtime.h>
#include <hip/hip_bf16.h>

#define B_   4
#define H_   16
#define L_   2048
#define D_   64
#define BH_  (B_ * H_)
#define CTX_SIZE ((size_t)BH_ * L_ * D_)   // 8,388,608 floats

// ---------------------------------------------------------------------------
// Kernel 1: raw scores S = Q @ K^T per head. 64x64 output tile per block.
// D=64 fits in a single LDS stage (no k-loop). Tiles stored transposed
// ([d][row], pad to 68 floats) so compute reads are aligned float4 and
// conflict-free (bank = (4d + 4t)%32, <=2-way).
// ---------------------------------------------------------------------------
__global__ __launch_bounds__(256) void k_scores(const float* __restrict__ Q,
                                                const float* __restrict__ Km,
                                                float* __restrict__ S) {
    __shared__ float sQT[D_][68];
    __shared__ float sKT[D_][68];
    const int bh = blockIdx.z;
    const int qt = blockIdx.y * 64;
    const int kt = blockIdx.x * 64;
    const int t  = threadIdx.x;
    const int c4 = t & 15;    // float4 column group 0..15
    const int r0 = t >> 4;    // row base 0..15

    for (int i = 0; i < 4; ++i) {
        const int r = r0 + 16 * i;
        float4 v = *(const float4*)&Q[((size_t)(bh * L_ + qt + r)) * D_ + 4 * c4];
        sQT[4 * c4 + 0][r] = v.x; sQT[4 * c4 + 1][r] = v.y;
        sQT[4 * c4 + 2][r] = v.z; sQT[4 * c4 + 3][r] = v.w;
        float4 w = *(const float4*)&Km[((size_t)(bh * L_ + kt + r)) * D_ + 4 * c4];
        sKT[4 * c4 + 0][r] = w.x; sKT[4 * c4 + 1][r] = w.y;
        sKT[4 * c4 + 2][r] = w.z; sKT[4 * c4 + 3][r] = w.w;
    }
    __syncthreads();

    const int tx = t & 15, ty = t >> 4;
    float acc[4][4] = {};
#pragma unroll 16
    for (int d = 0; d < D_; ++d) {
        float4 a = *(const float4*)&sQT[d][4 * ty];
        float4 b = *(const float4*)&sKT[d][4 * tx];
        const float av[4] = {a.x, a.y, a.z, a.w};
        const float bv[4] = {b.x, b.y, b.z, b.w};
#pragma unroll
        for (int i = 0; i < 4; ++i)
#pragma unroll
            for (int j = 0; j < 4; ++j) acc[i][j] += av[i] * bv[j];
    }

    for (int i = 0; i < 4; ++i) {
        const int row = qt + 4 * ty + i;
        float4 o = make_float4(acc[i][0], acc[i][1], acc[i][2], acc[i][3]);
        *(float4*)&S[((size_t)bh * L_ + row) * L_ + kt + 4 * tx] = o;
    }
}

// ---------------------------------------------------------------------------
// Kernel 2: in-place row softmax over the 2048-wide attn rows.
// One wave per row; 32 floats/lane held in registers; shfl reductions.
// ---------------------------------------------------------------------------
__global__ __launch_bounds__(256) void k_softmax(float* __restrict__ S) {
    const int  w    = threadIdx.x >> 6;
    const int  lane = threadIdx.x & 63;
    const size_t row = (size_t)blockIdx.x * 4 + w;   // 0 .. 131071
    float* p = S + row * L_;

    float4 v[8];
    float m = -1e30f;
#pragma unroll
    for (int i = 0; i < 8; ++i) {
        v[i] = *(const float4*)&p[i * 256 + lane * 4];
        m = fmaxf(m, fmaxf(fmaxf(v[i].x, v[i].y), fmaxf(v[i].z, v[i].w)));
    }
#pragma unroll
    for (int o = 32; o; o >>= 1) m = fmaxf(m, __shfl_xor(m, o));

    float s = 0.f;
#pragma unroll
    for (int i = 0; i < 8; ++i) {
        v[i].x = __expf(v[i].x - m); v[i].y = __expf(v[i].y - m);
        v[i].z = __expf(v[i].z - m); v[i].w = __expf(v[i].w - m);
        s += v[i].x + v[i].y + v[i].z + v[i].w;
    }
#pragma unroll
    for (int o = 32; o; o >>= 1) s += __shfl_xor(s, o);

    const float inv = 1.0f / s;
#pragma unroll
    for (int i = 0; i < 8; ++i) {
        v[i].x *= inv; v[i].y *= inv; v[i].z *= inv; v[i].w *= inv;
        *(float4*)&p[i * 256 + lane * 4] = v[i];
    }
}

// ---------------------------------------------------------------------------
// Kernel 3: context = P @ V per head. 64 rows x 64 cols (full D) per block,
// k-loop over 32 chunks of 64 keys. P staged transposed, V row-major (both
// pad 68).
// ---------------------------------------------------------------------------
__global__ __launch_bounds__(256) void k_context(const float* __restrict__ P,
                                                 const float* __restrict__ V,
                                                 float* __restrict__ O) {
    __shared__ float sPT[64][68];
    __shared__ float sV[64][68];
    const int bh = blockIdx.y;
    const int qt = blockIdx.x * 64;
    const int t  = threadIdx.x;
    const int c4 = t & 15;
    const int tx = t & 15, ty = t >> 4;

    float acc[4][4] = {};
    for (int ck = 0; ck < 32; ++ck) {
        __syncthreads();
        for (int i = 0; i < 4; ++i) {
            const int r = (t >> 4) + 16 * i;
            float4 v = *(const float4*)&P[((size_t)(bh * L_ + qt + r)) * L_ + ck * 64 + 4 * c4];
            sPT[4 * c4 + 0][r] = v.x; sPT[4 * c4 + 1][r] = v.y;
            sPT[4 * c4 + 2][r] = v.z; sPT[4 * c4 + 3][r] = v.w;
            float4 w = *(const float4*)&V[((size_t)(bh * L_ + ck * 64 + r)) * D_ + 4 * c4];
            *(float4*)&sV[r][4 * c4] = w;
        }
        __syncthreads();
#pragma unroll 16
        for (int kk = 0; kk < 64; ++kk) {
            float4 a = *(const float4*)&sPT[kk][4 * ty];
            float4 b = *(const float4*)&sV[kk][4 * tx];
            const float av[4] = {a.x, a.y, a.z, a.w};
            const float bv[4] = {b.x, b.y, b.z, b.w};
#pragma unroll
            for (int i = 0; i < 4; ++i)
#pragma unroll
                for (int j = 0; j < 4; ++j) acc[i][j] += av[i] * bv[j];
        }
    }

    for (int i = 0; i < 4; ++i) {
        float4 o = make_float4(acc[i][0], acc[i][1], acc[i][2], acc[i][3]);
        *(float4*)&O[((size_t)(bh * L_ + qt + 4 * ty + i)) * D_ + 4 * tx] = o;
    }
}

// ---------------------------------------------------------------------------
extern "C" void kernel_launch(void* const* d_in, const int* in_sizes, int n_in,
                              void* d_out, int out_size, void* d_ws, size_t ws_size,
                              hipStream_t stream) {
    const float* Q  = (const float*)d_in[0];
    const float* Km = (const float*)d_in[1];
    const float* V  = (const float*)d_in[2];
    float* out  = (float*)d_out;
    float* ctx  = out;                 // [B,H,L,D]
    float* attn = out + CTX_SIZE;      // [B,H,L,L]

    // 1) raw scores into attn region
    k_scores<<<dim3(L_ / 64, L_ / 64, BH_), 256, 0, stream>>>(Q, Km, attn);
    // 2) in-place softmax (131072 rows, 4 rows/block)
    k_softmax<<<dim3((BH_ * L_) / 4), 256, 0, stream>>>(attn);
    // 3) context = attn @ V
    k_context<<<dim3(L_ / 64, BH_), 256, 0, stream>>>(attn, V, ctx);
}